// Round 2
// baseline (501.645 us; speedup 1.0000x reference)
//
#include <hip/hip_runtime.h>
#include <hip/hip_bf16.h>

typedef __attribute__((ext_vector_type(4))) float f32x4;
typedef __attribute__((ext_vector_type(8))) short bf16x8;   // 8 bf16 in 4 VGPRs
typedef __attribute__((ext_vector_type(2))) unsigned int uint2v;

#define N_DETS  50000
#define E_PAIRS 1600000
#define NB64    (E_PAIRS / 64)   // 25000 64-edge blocks

// ---------- helpers ----------
__device__ __forceinline__ unsigned short f2bf(float f){
  union { float f; unsigned int u; } v; v.f = f;
  return (unsigned short)((v.u + 0x7FFFu + ((v.u >> 16) & 1u)) >> 16);  // RTNE
}

__device__ __forceinline__ bf16x8 pack8(f32x4 a, f32x4 b){
  union { unsigned int u[4]; bf16x8 v; } t;
  t.u[0] = (unsigned int)f2bf(a[0]) | ((unsigned int)f2bf(a[1]) << 16);
  t.u[1] = (unsigned int)f2bf(a[2]) | ((unsigned int)f2bf(a[3]) << 16);
  t.u[2] = (unsigned int)f2bf(b[0]) | ((unsigned int)f2bf(b[1]) << 16);
  t.u[3] = (unsigned int)f2bf(b[2]) | ((unsigned int)f2bf(b[3]) << 16);
  return t.v;
}

// ---------- kernel A: f1 = relu(det @ W1 + b1) -> bf16 ; blocks 0..39 also pack weights ----------
__global__ __launch_bounds__(256) void kA(const float* __restrict__ det,
                                          const float* __restrict__ W1,
                                          const float* __restrict__ b1,
                                          const float* __restrict__ Wp0,
                                          const float* __restrict__ Wp1,
                                          unsigned short* __restrict__ f1,
                                          unsigned short* __restrict__ wf){
  // folded kPack: 20 frags x 512 shorts = 10240 = 40 blocks x 256 threads
  if (blockIdx.x < 40){
    int i = blockIdx.x * 256 + threadIdx.x;
    int f = i >> 9;
    int l = (i >> 3) & 63;
    int j = i & 7;
    int plc = l & 15, pq = l >> 4;
    float v;
    if (f < 12){           // layer0 A = Wp0^T : lane holds A[plc][pq*8+j]
      int kt = f >> 2, ot = f & 3;
      v = Wp0[(kt*32 + pq*8 + j)*64 + ot*16 + plc];
    } else {               // layer1 B = Wp1 : lane holds B[pq*8+j][plc]
      int g = f - 12;
      int kt = g >> 2, n2 = g & 3;
      v = Wp1[(kt*32 + pq*8 + j)*64 + n2*16 + plc];
    }
    wf[i] = f2bf(v);
  }

  __shared__ float w[128*32];     // 16 KB
  __shared__ float dt[16][132];   // padded rows
  const int t  = threadIdx.x;
  const int r0 = blockIdx.x * 16;
  {
    const f32x4* ws = reinterpret_cast<const f32x4*>(W1);
    #pragma unroll
    for (int i = 0; i < 4; ++i)
      reinterpret_cast<f32x4*>(w)[t + 256*i] = ws[t + 256*i];
    #pragma unroll
    for (int i = 0; i < 2; ++i){
      int idx = t + 256*i;
      int row = idx >> 5, c4 = (idx & 31) * 4;
      *reinterpret_cast<f32x4*>(&dt[row][c4]) =
        *reinterpret_cast<const f32x4*>(&det[(size_t)(r0+row)*128 + c4]);
    }
  }
  __syncthreads();
  const int r = t >> 4, c2 = (t & 15) * 2;
  float s0 = b1[c2], s1 = b1[c2 + 1];
  #pragma unroll 8
  for (int k = 0; k < 128; ++k){
    float d = dt[r][k];
    s0 = fmaf(d, w[k*32 + c2],     s0);
    s1 = fmaf(d, w[k*32 + c2 + 1], s1);
  }
  s0 = fmaxf(s0, 0.f); s1 = fmaxf(s1, 0.f);
  unsigned int pk = (unsigned int)f2bf(s0) | ((unsigned int)f2bf(s1) << 16);
  *reinterpret_cast<unsigned int*>(&f1[(size_t)(r0+r)*32 + c2]) = pk;
}

// ---------- kernel B: pairwise MLP + segment max ----------
// Per wave: 64 edges (= 2 centers). Layer0 swapped: h1^T = Wp0^T @ comb^T (MFMA),
// processed one 16-edge tile (et) at a time to keep only 16 acc VGPRs live.
// h1 -> LDS [edge][out] bf16, XOR-swizzled. Layer1 per-center: h2 = h1 @ Wp1.
// In-register segment max -> pooled[center][64] fp32.
__global__ __launch_bounds__(256, 3) void kB(const float* __restrict__ pf,
                                             const int*   __restrict__ nIdxs,
                                             const unsigned short* __restrict__ f1,
                                             const unsigned short* __restrict__ wf,
                                             const float* __restrict__ bp0,
                                             const float* __restrict__ bp1,
                                             float* __restrict__ pooled){
  __shared__ __align__(16) unsigned short h1buf[4][4096];   // 8 KB per wave
  const int tid  = threadIdx.x;
  const int wid  = tid >> 6;
  const int lane = tid & 63;
  const int lc   = lane & 15;
  const int q    = lane >> 4;
  char* hb = reinterpret_cast<char*>(&h1buf[wid][0]);

  // resident weight fragments (wave-invariant): 48 + 32 VGPR
  const bf16x8* wfv = reinterpret_cast<const bf16x8*>(wf);
  bf16x8 A0[3][4], B1w[2][4];
  #pragma unroll
  for (int kt = 0; kt < 3; ++kt)
    #pragma unroll
    for (int ot = 0; ot < 4; ++ot)
      A0[kt][ot] = wfv[(kt*4 + ot)*64 + lane];
  #pragma unroll
  for (int kt = 0; kt < 2; ++kt)
    #pragma unroll
    for (int n2 = 0; n2 < 4; ++n2)
      B1w[kt][n2] = wfv[(12 + kt*4 + n2)*64 + lane];

  // biases: layer0 in C-frag layout (row = 16ot+4q+r); layer1 folded post-max (channel == lane)
  f32x4 bb0[4];
  #pragma unroll
  for (int ot = 0; ot < 4; ++ot)
    bb0[ot] = *reinterpret_cast<const f32x4*>(&bp0[ot*16 + q*4]);
  const float bb1s = bp1[lane];

  const int nwaves = gridDim.x * 4;   // 12500 -> exactly 2 iters/wave
  for (int b = blockIdx.x*4 + wid; b < NB64; b += nwaves){
    const int e0 = b * 64;

    // hoist the two-deep gather chain (nIdx -> f1[n]) for ALL et tiles
    int nid[4];
    #pragma unroll
    for (int et = 0; et < 4; ++et) nid[et] = nIdxs[e0 + et*16 + lc];
    bf16x8 f1n[4];
    #pragma unroll
    for (int et = 0; et < 4; ++et)
      f1n[et] = *reinterpret_cast<const bf16x8*>(&f1[(size_t)nid[et]*32 + q*8]);

    // ---- layer 0 (swapped), one et tile at a time: acc live = 16 VGPR ----
    #pragma unroll
    for (int et = 0; et < 4; ++et){
      const int eg = e0 + et*16 + lc;
      f32x4 p0 = *reinterpret_cast<const f32x4*>(&pf[(size_t)eg*32 + q*8]);
      f32x4 p1 = *reinterpret_cast<const f32x4*>(&pf[(size_t)eg*32 + q*8 + 4]);
      const int c = (e0 >> 5) + (et >> 1);     // center row, wave-uniform per et
      bf16x8 f1c = *reinterpret_cast<const bf16x8*>(&f1[(size_t)c*32 + q*8]);
      bf16x8 bfr0 = pack8(p0, p1);

      f32x4 acc[4];
      #pragma unroll
      for (int ot = 0; ot < 4; ++ot) acc[ot] = bb0[ot];
      #pragma unroll
      for (int ot = 0; ot < 4; ++ot){
        acc[ot] = __builtin_amdgcn_mfma_f32_16x16x32_bf16(A0[0][ot], bfr0,    acc[ot], 0,0,0);
        acc[ot] = __builtin_amdgcn_mfma_f32_16x16x32_bf16(A0[1][ot], f1c,     acc[ot], 0,0,0);
        acc[ot] = __builtin_amdgcn_mfma_f32_16x16x32_bf16(A0[2][ot], f1n[et], acc[ot], 0,0,0);
      }

      // relu -> bf16 -> LDS [edge][out], swizzle byte ^= (edge&7)<<4
      const int edge = et*16 + lc;
      const int swz  = (edge & 7) << 4;
      #pragma unroll
      for (int ot = 0; ot < 4; ++ot){
        f32x4 v = acc[ot];                       // r -> out = 16ot + 4q + r
        unsigned int lo = (unsigned int)f2bf(fmaxf(v[0],0.f)) | ((unsigned int)f2bf(fmaxf(v[1],0.f)) << 16);
        unsigned int hi = (unsigned int)f2bf(fmaxf(v[2],0.f)) | ((unsigned int)f2bf(fmaxf(v[3],0.f)) << 16);
        uint2v wv; wv[0] = lo; wv[1] = hi;
        *reinterpret_cast<uint2v*>(hb + ((edge*128 + ot*32 + q*8) ^ swz)) = wv;  // ds_write_b64
      }
    }

    // ---- layer 1 + segment max, one center (32 edges = 2 m-tiles) at a time ----
    const int cbase = e0 >> 5;
    #pragma unroll
    for (int cen = 0; cen < 2; ++cen){
      const int eA = (2*cen)*16 + lc;
      const int eB = (2*cen + 1)*16 + lc;
      const int sw = (lc & 7) << 4;            // eA&7 == eB&7 == lc&7
      bf16x8 a0A = *reinterpret_cast<const bf16x8*>(hb + ((eA*128      + q*16) ^ sw));
      bf16x8 a1A = *reinterpret_cast<const bf16x8*>(hb + ((eA*128 + 64 + q*16) ^ sw));
      bf16x8 a0B = *reinterpret_cast<const bf16x8*>(hb + ((eB*128      + q*16) ^ sw));
      bf16x8 a1B = *reinterpret_cast<const bf16x8*>(hb + ((eB*128 + 64 + q*16) ^ sw));

      f32x4 accA[4], accB[4];
      #pragma unroll
      for (int n2 = 0; n2 < 4; ++n2){
        f32x4 z = {0.f, 0.f, 0.f, 0.f};
        accA[n2] = z; accB[n2] = z;
      }
      #pragma unroll
      for (int n2 = 0; n2 < 4; ++n2){
        accA[n2] = __builtin_amdgcn_mfma_f32_16x16x32_bf16(a0A, B1w[0][n2], accA[n2], 0,0,0);
        accA[n2] = __builtin_amdgcn_mfma_f32_16x16x32_bf16(a1A, B1w[1][n2], accA[n2], 0,0,0);
        accB[n2] = __builtin_amdgcn_mfma_f32_16x16x32_bf16(a0B, B1w[0][n2], accB[n2], 0,0,0);
        accB[n2] = __builtin_amdgcn_mfma_f32_16x16x32_bf16(a1B, B1w[1][n2], accB[n2], 0,0,0);
      }

      float s0n, s1n, s2n, s3n;
      #pragma unroll
      for (int n2 = 0; n2 < 4; ++n2){
        float m0 = fmaxf(fmaxf(accA[n2][0], accB[n2][0]), fmaxf(accA[n2][1], accB[n2][1]));
        float m1 = fmaxf(fmaxf(accA[n2][2], accB[n2][2]), fmaxf(accA[n2][3], accB[n2][3]));
        float mm = fmaxf(m0, m1);
        mm = fmaxf(mm, __shfl_xor(mm, 16));
        mm = fmaxf(mm, __shfl_xor(mm, 32));
        if (n2 == 0) s0n = mm; else if (n2 == 1) s1n = mm; else if (n2 == 2) s2n = mm; else s3n = mm;
      }
      float v01 = (q & 1) ? s1n : s0n;
      float v23 = (q & 1) ? s3n : s2n;
      float v   = (q & 2) ? v23 : v01;   // select n2 == q -> out channel == lane
      v = fmaxf(v + bb1s, 0.f);          // bias folded after max (bias const per column)
      pooled[(size_t)(cbase + cen)*64 + lane] = v;
    }
  }
}

// ---------- kernel C: p=relu(pooled@Wq0+b); p=relu(p@Wq1+b); out=relu(det + p@Wo+bo) ----------
// Weights read straight from global (L1/L2-resident, 64 KB total) -> tiny LDS, high occupancy.
__global__ __launch_bounds__(256) void kC(const float* __restrict__ det,
                                          const float* __restrict__ pooled,
                                          const float* __restrict__ Wq0, const float* __restrict__ bq0,
                                          const float* __restrict__ Wq1, const float* __restrict__ bq1,
                                          const float* __restrict__ Wo,  const float* __restrict__ bo,
                                          float* __restrict__ out){
  __shared__ float pt[16*68];      // padded stride 68
  __shared__ float p1t[16*68];
  const int t  = threadIdx.x;
  const int r0 = blockIdx.x * 16;
  {
    int row = t >> 4, c4l = (t & 15) * 4;
    *reinterpret_cast<f32x4*>(&pt[row*68 + c4l]) =
      *reinterpret_cast<const f32x4*>(&pooled[(size_t)(r0+row)*64 + c4l]);
  }
  __syncthreads();
  const int r  = t >> 4;
  const int c4 = (t & 15) * 4;

  // q0
  f32x4 a = *reinterpret_cast<const f32x4*>(&bq0[c4]);
  #pragma unroll 8
  for (int k = 0; k < 64; ++k){
    float pd = pt[r*68 + k];
    f32x4 wv = *reinterpret_cast<const f32x4*>(&Wq0[k*64 + c4]);
    a[0] = fmaf(pd, wv[0], a[0]); a[1] = fmaf(pd, wv[1], a[1]);
    a[2] = fmaf(pd, wv[2], a[2]); a[3] = fmaf(pd, wv[3], a[3]);
  }
  a[0]=fmaxf(a[0],0.f); a[1]=fmaxf(a[1],0.f); a[2]=fmaxf(a[2],0.f); a[3]=fmaxf(a[3],0.f);
  *reinterpret_cast<f32x4*>(&p1t[r*68 + c4]) = a;
  __syncthreads();

  // q1
  f32x4 a2 = *reinterpret_cast<const f32x4*>(&bq1[c4]);
  #pragma unroll 8
  for (int k = 0; k < 64; ++k){
    float pd = p1t[r*68 + k];
    f32x4 wv = *reinterpret_cast<const f32x4*>(&Wq1[k*64 + c4]);
    a2[0] = fmaf(pd, wv[0], a2[0]); a2[1] = fmaf(pd, wv[1], a2[1]);
    a2[2] = fmaf(pd, wv[2], a2[2]); a2[3] = fmaf(pd, wv[3], a2[3]);
  }
  a2[0]=fmaxf(a2[0],0.f); a2[1]=fmaxf(a2[1],0.f); a2[2]=fmaxf(a2[2],0.f); a2[3]=fmaxf(a2[3],0.f);
  *reinterpret_cast<f32x4*>(&pt[r*68 + c4]) = a2;
  __syncthreads();

  // Wo + residual; this thread owns output cols c4..c4+3 and 64+c4..64+c4+3
  f32x4 o0 = *reinterpret_cast<const f32x4*>(&bo[c4]);
  f32x4 o1 = *reinterpret_cast<const f32x4*>(&bo[64 + c4]);
  #pragma unroll 8
  for (int k = 0; k < 64; ++k){
    float pd = pt[r*68 + k];
    f32x4 wa = *reinterpret_cast<const f32x4*>(&Wo[k*128 + c4]);
    f32x4 wb = *reinterpret_cast<const f32x4*>(&Wo[k*128 + 64 + c4]);
    o0[0] = fmaf(pd, wa[0], o0[0]); o0[1] = fmaf(pd, wa[1], o0[1]);
    o0[2] = fmaf(pd, wa[2], o0[2]); o0[3] = fmaf(pd, wa[3], o0[3]);
    o1[0] = fmaf(pd, wb[0], o1[0]); o1[1] = fmaf(pd, wb[1], o1[1]);
    o1[2] = fmaf(pd, wb[2], o1[2]); o1[3] = fmaf(pd, wb[3], o1[3]);
  }
  const float* dr = &det[(size_t)(r0 + r) * 128];
  f32x4 d0 = *reinterpret_cast<const f32x4*>(&dr[c4]);
  f32x4 d1 = *reinterpret_cast<const f32x4*>(&dr[64 + c4]);
  f32x4 res0, res1;
  res0[0]=fmaxf(d0[0]+o0[0],0.f); res0[1]=fmaxf(d0[1]+o0[1],0.f);
  res0[2]=fmaxf(d0[2]+o0[2],0.f); res0[3]=fmaxf(d0[3]+o0[3],0.f);
  res1[0]=fmaxf(d1[0]+o1[0],0.f); res1[1]=fmaxf(d1[1]+o1[1],0.f);
  res1[2]=fmaxf(d1[2]+o1[2],0.f); res1[3]=fmaxf(d1[3]+o1[3],0.f);
  float* orow = &out[(size_t)(r0 + r) * 128];
  *reinterpret_cast<f32x4*>(&orow[c4])      = res0;
  *reinterpret_cast<f32x4*>(&orow[64 + c4]) = res1;
}

// ---------- launch ----------
extern "C" void kernel_launch(void* const* d_in, const int* in_sizes, int n_in,
                              void* d_out, int out_size, void* d_ws, size_t ws_size,
                              hipStream_t stream){
  const float* det   = (const float*)d_in[0];
  // d_in[1] = cIdxs: repeat(arange(N_DETS), 32) — segments contiguous; not re-read
  const int*   nIdx  = (const int*)  d_in[2];
  const float* pfeat = (const float*)d_in[3];
  const float* W1    = (const float*)d_in[4];
  const float* b1    = (const float*)d_in[5];
  const float* Wp0   = (const float*)d_in[6];
  const float* bp0   = (const float*)d_in[7];
  const float* Wp1   = (const float*)d_in[8];
  const float* bp1   = (const float*)d_in[9];
  const float* Wq0   = (const float*)d_in[10];
  const float* bq0   = (const float*)d_in[11];
  const float* Wq1   = (const float*)d_in[12];
  const float* bq1   = (const float*)d_in[13];
  const float* Wo    = (const float*)d_in[14];
  const float* bo    = (const float*)d_in[15];
  float* out = (float*)d_out;

  // workspace: f1 bf16 3.2MB | packed weights 20KB | pooled fp32 12.8MB
  unsigned short* f1 = (unsigned short*)d_ws;
  unsigned short* wf = (unsigned short*)((char*)d_ws + 3200000);
  float* pooled      = (float*)((char*)d_ws + 3225600);

  kA<<<N_DETS/16, 256, 0, stream>>>(det, W1, b1, Wp0, Wp1, f1, wf);
  kB<<<3125,      256, 0, stream>>>(pfeat, nIdx, f1, wf, bp0, bp1, pooled);
  kC<<<N_DETS/16, 256, 0, stream>>>(det, pooled, Wq0, bq0, Wq1, bq1, Wo, bo, out);
}

// Round 3
// 426.725 us; speedup vs baseline: 1.1756x; 1.1756x over previous
//
#include <hip/hip_runtime.h>
#include <hip/hip_bf16.h>

typedef __attribute__((ext_vector_type(4))) float f32x4;
typedef __attribute__((ext_vector_type(8))) short bf16x8;   // 8 bf16 in 4 VGPRs
typedef __attribute__((ext_vector_type(2))) unsigned int uint2v;

#define N_DETS  50000
#define E_PAIRS 1600000
#define NB64    (E_PAIRS / 64)   // 25000 64-edge blocks

// ---------- helpers ----------
__device__ __forceinline__ unsigned short f2bf(float f){
  union { float f; unsigned int u; } v; v.f = f;
  return (unsigned short)((v.u + 0x7FFFu + ((v.u >> 16) & 1u)) >> 16);  // RTNE
}

__device__ __forceinline__ bf16x8 pack8(f32x4 a, f32x4 b){
  union { unsigned int u[4]; bf16x8 v; } t;
  t.u[0] = (unsigned int)f2bf(a[0]) | ((unsigned int)f2bf(a[1]) << 16);
  t.u[1] = (unsigned int)f2bf(a[2]) | ((unsigned int)f2bf(a[3]) << 16);
  t.u[2] = (unsigned int)f2bf(b[0]) | ((unsigned int)f2bf(b[1]) << 16);
  t.u[3] = (unsigned int)f2bf(b[2]) | ((unsigned int)f2bf(b[3]) << 16);
  return t.v;
}

// ---------- kernel A: f1 = relu(det @ W1 + b1) -> bf16 ; blocks 0..39 also pack weights ----------
__global__ __launch_bounds__(256) void kA(const float* __restrict__ det,
                                          const float* __restrict__ W1,
                                          const float* __restrict__ b1,
                                          const float* __restrict__ Wp0,
                                          const float* __restrict__ Wp1,
                                          unsigned short* __restrict__ f1,
                                          unsigned short* __restrict__ wf){
  // folded kPack: 20 frags x 512 shorts = 10240 = 40 blocks x 256 threads
  if (blockIdx.x < 40){
    int i = blockIdx.x * 256 + threadIdx.x;
    int f = i >> 9;
    int l = (i >> 3) & 63;
    int j = i & 7;
    int plc = l & 15, pq = l >> 4;
    float v;
    if (f < 12){           // layer0 A = Wp0^T : lane holds A[plc][pq*8+j]
      int kt = f >> 2, ot = f & 3;
      v = Wp0[(kt*32 + pq*8 + j)*64 + ot*16 + plc];
    } else {               // layer1 B = Wp1 : lane holds B[pq*8+j][plc]
      int g = f - 12;
      int kt = g >> 2, n2 = g & 3;
      v = Wp1[(kt*32 + pq*8 + j)*64 + n2*16 + plc];
    }
    wf[i] = f2bf(v);
  }

  __shared__ float w[128*32];     // 16 KB
  __shared__ float dt[16][132];   // padded rows
  const int t  = threadIdx.x;
  const int r0 = blockIdx.x * 16;
  {
    const f32x4* ws = reinterpret_cast<const f32x4*>(W1);
    #pragma unroll
    for (int i = 0; i < 4; ++i)
      reinterpret_cast<f32x4*>(w)[t + 256*i] = ws[t + 256*i];
    #pragma unroll
    for (int i = 0; i < 2; ++i){
      int idx = t + 256*i;
      int row = idx >> 5, c4 = (idx & 31) * 4;
      *reinterpret_cast<f32x4*>(&dt[row][c4]) =
        *reinterpret_cast<const f32x4*>(&det[(size_t)(r0+row)*128 + c4]);
    }
  }
  __syncthreads();
  const int r = t >> 4, c2 = (t & 15) * 2;
  float s0 = b1[c2], s1 = b1[c2 + 1];
  #pragma unroll 8
  for (int k = 0; k < 128; ++k){
    float d = dt[r][k];
    s0 = fmaf(d, w[k*32 + c2],     s0);
    s1 = fmaf(d, w[k*32 + c2 + 1], s1);
  }
  s0 = fmaxf(s0, 0.f); s1 = fmaxf(s1, 0.f);
  unsigned int pk = (unsigned int)f2bf(s0) | ((unsigned int)f2bf(s1) << 16);
  *reinterpret_cast<unsigned int*>(&f1[(size_t)(r0+r)*32 + c2]) = pk;
}

// ---------- kernel B: pairwise MLP + segment max ----------
// Per wave: 64 edges (= 2 centers), 2 iterations per wave.
// __launch_bounds__(256,2): 256-VGPR budget so weight fragments (80 VGPR) and the
// whole iteration's prefetched inputs (~80 VGPR) stay RESIDENT — no spill/remat.
__global__ __launch_bounds__(256, 2) void kB(const float* __restrict__ pf,
                                             const int*   __restrict__ nIdxs,
                                             const unsigned short* __restrict__ f1,
                                             const unsigned short* __restrict__ wf,
                                             const float* __restrict__ bp0,
                                             const float* __restrict__ bp1,
                                             float* __restrict__ pooled){
  __shared__ __align__(16) unsigned short h1buf[4][4096];   // 8 KB per wave
  const int tid  = threadIdx.x;
  const int wid  = tid >> 6;
  const int lane = tid & 63;
  const int lc   = lane & 15;
  const int q    = lane >> 4;
  char* hb = reinterpret_cast<char*>(&h1buf[wid][0]);

  // resident weight fragments (wave-invariant): 48 + 32 VGPR
  const bf16x8* wfv = reinterpret_cast<const bf16x8*>(wf);
  bf16x8 A0[3][4], B1w[2][4];
  #pragma unroll
  for (int kt = 0; kt < 3; ++kt)
    #pragma unroll
    for (int ot = 0; ot < 4; ++ot)
      A0[kt][ot] = wfv[(kt*4 + ot)*64 + lane];
  #pragma unroll
  for (int kt = 0; kt < 2; ++kt)
    #pragma unroll
    for (int n2 = 0; n2 < 4; ++n2)
      B1w[kt][n2] = wfv[(12 + kt*4 + n2)*64 + lane];

  // biases: layer0 in C-frag layout (row = 16ot+4q+r); layer1 folded post-max (channel == lane)
  f32x4 bb0[4];
  #pragma unroll
  for (int ot = 0; ot < 4; ++ot)
    bb0[ot] = *reinterpret_cast<const f32x4*>(&bp0[ot*16 + q*4]);
  const float bb1s = bp1[lane];

  const int nwaves = gridDim.x * 4;   // 12500 -> exactly 2 iters/wave
  for (int b = blockIdx.x*4 + wid; b < NB64; b += nwaves){
    const int e0 = b * 64;
    const int cbase = e0 >> 5;

    // ---- prefetch EVERYTHING for this 64-edge block up front ----
    int nid[4];
    #pragma unroll
    for (int et = 0; et < 4; ++et) nid[et] = nIdxs[e0 + et*16 + lc];
    f32x4 pfv[4][2];
    #pragma unroll
    for (int et = 0; et < 4; ++et){
      pfv[et][0] = *reinterpret_cast<const f32x4*>(&pf[(size_t)(e0 + et*16 + lc)*32 + q*8]);
      pfv[et][1] = *reinterpret_cast<const f32x4*>(&pf[(size_t)(e0 + et*16 + lc)*32 + q*8 + 4]);
    }
    bf16x8 f1c[2];
    #pragma unroll
    for (int s = 0; s < 2; ++s)
      f1c[s] = *reinterpret_cast<const bf16x8*>(&f1[(size_t)(cbase + s)*32 + q*8]);
    bf16x8 f1n[4];
    #pragma unroll
    for (int et = 0; et < 4; ++et)
      f1n[et] = *reinterpret_cast<const bf16x8*>(&f1[(size_t)nid[et]*32 + q*8]);

    // ---- layer 0 (swapped), one et tile at a time: acc live = 16 VGPR ----
    #pragma unroll
    for (int et = 0; et < 4; ++et){
      bf16x8 bfr0 = pack8(pfv[et][0], pfv[et][1]);

      f32x4 acc[4];
      #pragma unroll
      for (int ot = 0; ot < 4; ++ot) acc[ot] = bb0[ot];
      #pragma unroll
      for (int ot = 0; ot < 4; ++ot){
        acc[ot] = __builtin_amdgcn_mfma_f32_16x16x32_bf16(A0[0][ot], bfr0,       acc[ot], 0,0,0);
        acc[ot] = __builtin_amdgcn_mfma_f32_16x16x32_bf16(A0[1][ot], f1c[et>>1], acc[ot], 0,0,0);
        acc[ot] = __builtin_amdgcn_mfma_f32_16x16x32_bf16(A0[2][ot], f1n[et],    acc[ot], 0,0,0);
      }

      // relu -> bf16 -> LDS [edge][out], swizzle byte ^= (edge&7)<<4
      const int edge = et*16 + lc;
      const int swz  = (edge & 7) << 4;
      #pragma unroll
      for (int ot = 0; ot < 4; ++ot){
        f32x4 v = acc[ot];                       // r -> out = 16ot + 4q + r
        unsigned int lo = (unsigned int)f2bf(fmaxf(v[0],0.f)) | ((unsigned int)f2bf(fmaxf(v[1],0.f)) << 16);
        unsigned int hi = (unsigned int)f2bf(fmaxf(v[2],0.f)) | ((unsigned int)f2bf(fmaxf(v[3],0.f)) << 16);
        uint2v wv; wv[0] = lo; wv[1] = hi;
        *reinterpret_cast<uint2v*>(hb + ((edge*128 + ot*32 + q*8) ^ swz)) = wv;  // ds_write_b64
      }
    }

    // ---- layer 1 + segment max, one center (32 edges = 2 m-tiles) at a time ----
    #pragma unroll
    for (int cen = 0; cen < 2; ++cen){
      const int eA = (2*cen)*16 + lc;
      const int eB = (2*cen + 1)*16 + lc;
      const int sw = (lc & 7) << 4;            // eA&7 == eB&7 == lc&7
      bf16x8 a0A = *reinterpret_cast<const bf16x8*>(hb + ((eA*128      + q*16) ^ sw));
      bf16x8 a1A = *reinterpret_cast<const bf16x8*>(hb + ((eA*128 + 64 + q*16) ^ sw));
      bf16x8 a0B = *reinterpret_cast<const bf16x8*>(hb + ((eB*128      + q*16) ^ sw));
      bf16x8 a1B = *reinterpret_cast<const bf16x8*>(hb + ((eB*128 + 64 + q*16) ^ sw));

      f32x4 accA[4], accB[4];
      #pragma unroll
      for (int n2 = 0; n2 < 4; ++n2){
        f32x4 z = {0.f, 0.f, 0.f, 0.f};
        accA[n2] = z; accB[n2] = z;
      }
      #pragma unroll
      for (int n2 = 0; n2 < 4; ++n2){
        accA[n2] = __builtin_amdgcn_mfma_f32_16x16x32_bf16(a0A, B1w[0][n2], accA[n2], 0,0,0);
        accA[n2] = __builtin_amdgcn_mfma_f32_16x16x32_bf16(a1A, B1w[1][n2], accA[n2], 0,0,0);
        accB[n2] = __builtin_amdgcn_mfma_f32_16x16x32_bf16(a0B, B1w[0][n2], accB[n2], 0,0,0);
        accB[n2] = __builtin_amdgcn_mfma_f32_16x16x32_bf16(a1B, B1w[1][n2], accB[n2], 0,0,0);
      }

      float s0n, s1n, s2n, s3n;
      #pragma unroll
      for (int n2 = 0; n2 < 4; ++n2){
        float m0 = fmaxf(fmaxf(accA[n2][0], accB[n2][0]), fmaxf(accA[n2][1], accB[n2][1]));
        float m1 = fmaxf(fmaxf(accA[n2][2], accB[n2][2]), fmaxf(accA[n2][3], accB[n2][3]));
        float mm = fmaxf(m0, m1);
        mm = fmaxf(mm, __shfl_xor(mm, 16));
        mm = fmaxf(mm, __shfl_xor(mm, 32));
        if (n2 == 0) s0n = mm; else if (n2 == 1) s1n = mm; else if (n2 == 2) s2n = mm; else s3n = mm;
      }
      float v01 = (q & 1) ? s1n : s0n;
      float v23 = (q & 1) ? s3n : s2n;
      float v   = (q & 2) ? v23 : v01;   // select n2 == q -> out channel == lane
      v = fmaxf(v + bb1s, 0.f);          // bias folded after max (bias const per column)
      pooled[(size_t)(cbase + cen)*64 + lane] = v;
    }
  }
}

// ---------- kernel C: p=relu(pooled@Wq0+b); p=relu(p@Wq1+b); out=relu(det + p@Wo+bo) ----------
__global__ __launch_bounds__(256) void kC(const float* __restrict__ det,
                                          const float* __restrict__ pooled,
                                          const float* __restrict__ Wq0, const float* __restrict__ bq0,
                                          const float* __restrict__ Wq1, const float* __restrict__ bq1,
                                          const float* __restrict__ Wo,  const float* __restrict__ bo,
                                          float* __restrict__ out){
  __shared__ float w0[4096];
  __shared__ float w1[4096];
  __shared__ float wo2[8192];
  __shared__ float bb[256];        // bq0 | bq1 | bo
  __shared__ float pt[16*68];      // padded stride 68
  __shared__ float p1t[16*68];
  const int t  = threadIdx.x;
  const int r0 = blockIdx.x * 16;
  {
    const f32x4* s0 = reinterpret_cast<const f32x4*>(Wq0);
    const f32x4* s1 = reinterpret_cast<const f32x4*>(Wq1);
    const f32x4* s2 = reinterpret_cast<const f32x4*>(Wo);
    #pragma unroll
    for (int i = 0; i < 4; ++i) reinterpret_cast<f32x4*>(w0)[t + 256*i] = s0[t + 256*i];
    #pragma unroll
    for (int i = 0; i < 4; ++i) reinterpret_cast<f32x4*>(w1)[t + 256*i] = s1[t + 256*i];
    #pragma unroll
    for (int i = 0; i < 8; ++i) reinterpret_cast<f32x4*>(wo2)[t + 256*i] = s2[t + 256*i];
    if (t < 64)       bb[t] = bq0[t];
    else if (t < 128) bb[t] = bq1[t - 64];
    else              bb[t] = bo[t - 128];
    int row = t >> 4, c4l = (t & 15) * 4;
    *reinterpret_cast<f32x4*>(&pt[row*68 + c4l]) =
      *reinterpret_cast<const f32x4*>(&pooled[(size_t)(r0+row)*64 + c4l]);
  }
  __syncthreads();
  const int r  = t >> 4;
  const int c4 = (t & 15) * 4;

  // q0
  f32x4 a = *reinterpret_cast<const f32x4*>(&bb[c4]);
  #pragma unroll 8
  for (int k = 0; k < 64; ++k){
    float pd = pt[r*68 + k];
    f32x4 wv = *reinterpret_cast<const f32x4*>(&w0[k*64 + c4]);
    a[0] = fmaf(pd, wv[0], a[0]); a[1] = fmaf(pd, wv[1], a[1]);
    a[2] = fmaf(pd, wv[2], a[2]); a[3] = fmaf(pd, wv[3], a[3]);
  }
  a[0]=fmaxf(a[0],0.f); a[1]=fmaxf(a[1],0.f); a[2]=fmaxf(a[2],0.f); a[3]=fmaxf(a[3],0.f);
  *reinterpret_cast<f32x4*>(&p1t[r*68 + c4]) = a;
  __syncthreads();

  // q1
  f32x4 a2 = *reinterpret_cast<const f32x4*>(&bb[64 + c4]);
  #pragma unroll 8
  for (int k = 0; k < 64; ++k){
    float pd = p1t[r*68 + k];
    f32x4 wv = *reinterpret_cast<const f32x4*>(&w1[k*64 + c4]);
    a2[0] = fmaf(pd, wv[0], a2[0]); a2[1] = fmaf(pd, wv[1], a2[1]);
    a2[2] = fmaf(pd, wv[2], a2[2]); a2[3] = fmaf(pd, wv[3], a2[3]);
  }
  a2[0]=fmaxf(a2[0],0.f); a2[1]=fmaxf(a2[1],0.f); a2[2]=fmaxf(a2[2],0.f); a2[3]=fmaxf(a2[3],0.f);
  *reinterpret_cast<f32x4*>(&pt[r*68 + c4]) = a2;
  __syncthreads();

  // Wo + residual; this thread owns output cols c4..c4+3 and 64+c4..64+c4+3
  f32x4 o0 = *reinterpret_cast<const f32x4*>(&bb[128 + c4]);
  f32x4 o1 = *reinterpret_cast<const f32x4*>(&bb[128 + 64 + c4]);
  #pragma unroll 8
  for (int k = 0; k < 64; ++k){
    float pd = pt[r*68 + k];
    f32x4 wa = *reinterpret_cast<const f32x4*>(&wo2[k*128 + c4]);
    f32x4 wb = *reinterpret_cast<const f32x4*>(&wo2[k*128 + 64 + c4]);
    o0[0] = fmaf(pd, wa[0], o0[0]); o0[1] = fmaf(pd, wa[1], o0[1]);
    o0[2] = fmaf(pd, wa[2], o0[2]); o0[3] = fmaf(pd, wa[3], o0[3]);
    o1[0] = fmaf(pd, wb[0], o1[0]); o1[1] = fmaf(pd, wb[1], o1[1]);
    o1[2] = fmaf(pd, wb[2], o1[2]); o1[3] = fmaf(pd, wb[3], o1[3]);
  }
  const float* dr = &det[(size_t)(r0 + r) * 128];
  f32x4 d0 = *reinterpret_cast<const f32x4*>(&dr[c4]);
  f32x4 d1 = *reinterpret_cast<const f32x4*>(&dr[64 + c4]);
  f32x4 res0, res1;
  res0[0]=fmaxf(d0[0]+o0[0],0.f); res0[1]=fmaxf(d0[1]+o0[1],0.f);
  res0[2]=fmaxf(d0[2]+o0[2],0.f); res0[3]=fmaxf(d0[3]+o0[3],0.f);
  res1[0]=fmaxf(d1[0]+o1[0],0.f); res1[1]=fmaxf(d1[1]+o1[1],0.f);
  res1[2]=fmaxf(d1[2]+o1[2],0.f); res1[3]=fmaxf(d1[3]+o1[3],0.f);
  float* orow = &out[(size_t)(r0 + r) * 128];
  *reinterpret_cast<f32x4*>(&orow[c4])      = res0;
  *reinterpret_cast<f32x4*>(&orow[64 + c4]) = res1;
}

// ---------- launch ----------
extern "C" void kernel_launch(void* const* d_in, const int* in_sizes, int n_in,
                              void* d_out, int out_size, void* d_ws, size_t ws_size,
                              hipStream_t stream){
  const float* det   = (const float*)d_in[0];
  // d_in[1] = cIdxs: repeat(arange(N_DETS), 32) — segments contiguous; not re-read
  const int*   nIdx  = (const int*)  d_in[2];
  const float* pfeat = (const float*)d_in[3];
  const float* W1    = (const float*)d_in[4];
  const float* b1    = (const float*)d_in[5];
  const float* Wp0   = (const float*)d_in[6];
  const float* bp0   = (const float*)d_in[7];
  const float* Wp1   = (const float*)d_in[8];
  const float* bp1   = (const float*)d_in[9];
  const float* Wq0   = (const float*)d_in[10];
  const float* bq0   = (const float*)d_in[11];
  const float* Wq1   = (const float*)d_in[12];
  const float* bq1   = (const float*)d_in[13];
  const float* Wo    = (const float*)d_in[14];
  const float* bo    = (const float*)d_in[15];
  float* out = (float*)d_out;

  // workspace: f1 bf16 3.2MB | packed weights 20KB | pooled fp32 12.8MB
  unsigned short* f1 = (unsigned short*)d_ws;
  unsigned short* wf = (unsigned short*)((char*)d_ws + 3200000);
  float* pooled      = (float*)((char*)d_ws + 3225600);

  kA<<<N_DETS/16, 256, 0, stream>>>(det, W1, b1, Wp0, Wp1, f1, wf);
  kB<<<3125,      256, 0, stream>>>(pfeat, nIdx, f1, wf, bp0, bp1, pooled);
  kC<<<N_DETS/16, 256, 0, stream>>>(det, pooled, Wq0, bq0, Wq1, bq1, Wo, bo, out);
}

// Round 4
// 410.722 us; speedup vs baseline: 1.2214x; 1.0390x over previous
//
#include <hip/hip_runtime.h>
#include <hip/hip_bf16.h>

typedef __attribute__((ext_vector_type(4))) float f32x4;
typedef __attribute__((ext_vector_type(8))) short bf16x8;   // 8 bf16 in 4 VGPRs
typedef __attribute__((ext_vector_type(2))) unsigned int uint2v;

#define N_DETS  50000
#define E_PAIRS 1600000
#define NB64    (E_PAIRS / 64)   // 25000 64-edge blocks

// ---------- helpers ----------
__device__ __forceinline__ unsigned int cvtpk(float lo, float hi){
  unsigned int r;                                   // dst[15:0]=bf16(lo), dst[31:16]=bf16(hi), RTNE
  asm("v_cvt_pk_bf16_f32 %0, %1, %2" : "=v"(r) : "v"(lo), "v"(hi));
  return r;
}

__device__ __forceinline__ unsigned short f2bf(float f){
  union { float f; unsigned int u; } v; v.f = f;
  return (unsigned short)((v.u + 0x7FFFu + ((v.u >> 16) & 1u)) >> 16);  // RTNE (pack path only)
}

__device__ __forceinline__ bf16x8 pack8v(f32x4 a, f32x4 b){
  union { unsigned int u[4]; bf16x8 v; } t;
  t.u[0] = cvtpk(a[0], a[1]);
  t.u[1] = cvtpk(a[2], a[3]);
  t.u[2] = cvtpk(b[0], b[1]);
  t.u[3] = cvtpk(b[2], b[3]);
  return t.v;
}

// ---------- kernel A: f1 = relu(det @ W1 + b1) -> bf16 ; blocks 0..39 also pack weights ----------
// 64 rows/block, 4 rows x 2 cols per thread (register blocking cuts LDS scalar reads ~3x).
__global__ __launch_bounds__(256) void kA(const float* __restrict__ det,
                                          const float* __restrict__ W1,
                                          const float* __restrict__ b1,
                                          const float* __restrict__ Wp0,
                                          const float* __restrict__ Wp1,
                                          unsigned short* __restrict__ f1,
                                          unsigned short* __restrict__ wf){
  // folded kPack: 20 frags x 512 shorts = 10240 = 40 blocks x 256 threads
  if (blockIdx.x < 40){
    int i = blockIdx.x * 256 + threadIdx.x;
    int f = i >> 9;
    int l = (i >> 3) & 63;
    int j = i & 7;
    int plc = l & 15, pq = l >> 4;
    float v;
    if (f < 12){           // layer0 A = Wp0^T : lane holds A[plc][pq*8+j]
      int kt = f >> 2, ot = f & 3;
      v = Wp0[(kt*32 + pq*8 + j)*64 + ot*16 + plc];
    } else {               // layer1 B = Wp1 : lane holds B[pq*8+j][plc]
      int g = f - 12;
      int kt = g >> 2, n2 = g & 3;
      v = Wp1[(kt*32 + pq*8 + j)*64 + n2*16 + plc];
    }
    wf[i] = f2bf(v);
  }

  __shared__ float w[128*32];      // [k][c], 16 KB
  __shared__ float dt[64*132];     // 64 rows, stride 132 (16B-aligned, 2-way banks), 33.8 KB
  const int t  = threadIdx.x;
  const int r0 = blockIdx.x * 64;
  {
    const f32x4* ws = reinterpret_cast<const f32x4*>(W1);
    #pragma unroll
    for (int i = 0; i < 4; ++i)
      reinterpret_cast<f32x4*>(w)[t + 256*i] = ws[t + 256*i];
    #pragma unroll
    for (int i = 0; i < 8; ++i){
      int idx = t + 256*i;                 // 0..2047
      int row = idx >> 5, c4 = (idx & 31) * 4;
      int gr = r0 + row; if (gr > N_DETS-1) gr = N_DETS-1;
      *reinterpret_cast<f32x4*>(&dt[row*132 + c4]) =
        *reinterpret_cast<const f32x4*>(&det[(size_t)gr*128 + c4]);
    }
  }
  __syncthreads();
  const int rg = t >> 4;               // rows rg*4 .. rg*4+3
  const int c2 = (t & 15) * 2;
  const float bw0 = b1[c2], bw1 = b1[c2 + 1];
  float a0[4], a1[4];
  #pragma unroll
  for (int i = 0; i < 4; ++i){ a0[i] = bw0; a1[i] = bw1; }
  for (int k4 = 0; k4 < 32; ++k4){
    f32x4 dv[4];
    #pragma unroll
    for (int i = 0; i < 4; ++i)
      dv[i] = *reinterpret_cast<const f32x4*>(&dt[(rg*4+i)*132 + k4*4]);
    #pragma unroll
    for (int kk = 0; kk < 4; ++kk){
      float w0v = w[(k4*4+kk)*32 + c2];
      float w1v = w[(k4*4+kk)*32 + c2 + 1];
      #pragma unroll
      for (int i = 0; i < 4; ++i){
        a0[i] = fmaf(dv[i][kk], w0v, a0[i]);
        a1[i] = fmaf(dv[i][kk], w1v, a1[i]);
      }
    }
  }
  #pragma unroll
  for (int i = 0; i < 4; ++i){
    int gr = r0 + rg*4 + i;
    if (gr < N_DETS){
      unsigned int pk = cvtpk(fmaxf(a0[i], 0.f), fmaxf(a1[i], 0.f));
      *reinterpret_cast<unsigned int*>(&f1[(size_t)gr*32 + c2]) = pk;
    }
  }
}

// ---------- kernel B: pairwise MLP + segment max (software-pipelined) ----------
// Per wave: 64 edges (= 2 centers), ~8 iterations. Loop-carried prefetch: next
// block's nIdx/pf/f1c issue right after current values are consumed, hiding HBM
// latency under layer0+layer1. B1w + bias0 fragments live in block-shared LDS
// (racy identical writes) to cut resident VGPRs -> 3 waves/SIMD.
__global__ __launch_bounds__(256, 3) void kB(const float* __restrict__ pf,
                                             const int*   __restrict__ nIdxs,
                                             const unsigned short* __restrict__ f1,
                                             const unsigned short* __restrict__ wf,
                                             const float* __restrict__ bp0,
                                             const float* __restrict__ bp1,
                                             float* __restrict__ pooled){
  __shared__ __align__(16) unsigned short h1buf[4][4096];    // 32 KB (8 KB/wave)
  __shared__ __align__(16) unsigned short b1w_lds[8*64*8];   // 8 KB: layer1 B frags
  __shared__ __align__(16) float bias0_lds[4*64*4];          // 4 KB: layer0 bias frags
  const int tid  = threadIdx.x;
  const int wid  = tid >> 6;
  const int lane = tid & 63;
  const int lc   = lane & 15;
  const int q    = lane >> 4;
  char* hb = reinterpret_cast<char*>(&h1buf[wid][0]);

  const bf16x8* wfv = reinterpret_cast<const bf16x8*>(wf);
  // layer0 A fragments resident (48 VGPR)
  bf16x8 A0[3][4];
  #pragma unroll
  for (int kt = 0; kt < 3; ++kt)
    #pragma unroll
    for (int ot = 0; ot < 4; ++ot)
      A0[kt][ot] = wfv[(kt*4 + ot)*64 + lane];
  // block-shared copies (every wave writes identical bytes; each wave reads only
  // addresses it wrote itself -> no barrier needed)
  #pragma unroll
  for (int g = 0; g < 8; ++g)
    *reinterpret_cast<bf16x8*>(&b1w_lds[(g*64 + lane)*8]) = wfv[(12 + g)*64 + lane];
  #pragma unroll
  for (int ot = 0; ot < 4; ++ot)
    *reinterpret_cast<f32x4*>(&bias0_lds[(ot*64 + lane)*4]) =
      *reinterpret_cast<const f32x4*>(&bp0[ot*16 + q*4]);
  const float bb1s = bp1[lane];

  const int stride = gridDim.x * 4;     // 3072 waves
  int b = blockIdx.x*4 + wid;

  // prologue: loads for first block
  int nid[4]; f32x4 pfv[4][2]; bf16x8 f1cv[2];
  {
    const int e0 = b * 64;
    #pragma unroll
    for (int et = 0; et < 4; ++et) nid[et] = nIdxs[e0 + et*16 + lc];
    #pragma unroll
    for (int et = 0; et < 4; ++et){
      pfv[et][0] = *reinterpret_cast<const f32x4*>(&pf[(size_t)(e0 + et*16 + lc)*32 + q*8]);
      pfv[et][1] = *reinterpret_cast<const f32x4*>(&pf[(size_t)(e0 + et*16 + lc)*32 + q*8 + 4]);
    }
    #pragma unroll
    for (int s = 0; s < 2; ++s)
      f1cv[s] = *reinterpret_cast<const bf16x8*>(&f1[(size_t)(b*2 + s)*32 + q*8]);
  }

  while (b < NB64){
    const int cbase = b * 2;

    // current-block gathers (nid arrived ~a full iteration ago)
    bf16x8 f1n[4];
    #pragma unroll
    for (int et = 0; et < 4; ++et)
      f1n[et] = *reinterpret_cast<const bf16x8*>(&f1[(size_t)nid[et]*32 + q*8]);
    // convert pf -> bf16 (consumes pfv)
    bf16x8 bfr[4];
    #pragma unroll
    for (int et = 0; et < 4; ++et) bfr[et] = pack8v(pfv[et][0], pfv[et][1]);
    bf16x8 f1c_cur0 = f1cv[0], f1c_cur1 = f1cv[1];

    // issue NEXT block's loads now; latency hides under layer0+layer1
    const int bn = b + stride;
    const int bl = (bn < NB64) ? bn : b;     // tail: harmless reload of current
    {
      const int e0n = bl * 64;
      #pragma unroll
      for (int et = 0; et < 4; ++et) nid[et] = nIdxs[e0n + et*16 + lc];
      #pragma unroll
      for (int et = 0; et < 4; ++et){
        pfv[et][0] = *reinterpret_cast<const f32x4*>(&pf[(size_t)(e0n + et*16 + lc)*32 + q*8]);
        pfv[et][1] = *reinterpret_cast<const f32x4*>(&pf[(size_t)(e0n + et*16 + lc)*32 + q*8 + 4]);
      }
      #pragma unroll
      for (int s = 0; s < 2; ++s)
        f1cv[s] = *reinterpret_cast<const bf16x8*>(&f1[(size_t)(bl*2 + s)*32 + q*8]);
    }

    // ---- layer 0 (swapped), one et tile at a time ----
    #pragma unroll
    for (int et = 0; et < 4; ++et){
      f32x4 acc[4];
      #pragma unroll
      for (int ot = 0; ot < 4; ++ot)
        acc[ot] = *reinterpret_cast<const f32x4*>(&bias0_lds[(ot*64 + lane)*4]);
      bf16x8 f1cc = (et < 2) ? f1c_cur0 : f1c_cur1;
      #pragma unroll
      for (int ot = 0; ot < 4; ++ot){
        acc[ot] = __builtin_amdgcn_mfma_f32_16x16x32_bf16(A0[0][ot], bfr[et], acc[ot], 0,0,0);
        acc[ot] = __builtin_amdgcn_mfma_f32_16x16x32_bf16(A0[1][ot], f1cc,    acc[ot], 0,0,0);
        acc[ot] = __builtin_amdgcn_mfma_f32_16x16x32_bf16(A0[2][ot], f1n[et], acc[ot], 0,0,0);
      }
      // relu -> bf16 -> LDS [edge][out], swizzle byte ^= (edge&7)<<4
      const int edge = et*16 + lc;
      const int swz  = (edge & 7) << 4;
      #pragma unroll
      for (int ot = 0; ot < 4; ++ot){
        uint2v wv;
        wv[0] = cvtpk(fmaxf(acc[ot][0], 0.f), fmaxf(acc[ot][1], 0.f));
        wv[1] = cvtpk(fmaxf(acc[ot][2], 0.f), fmaxf(acc[ot][3], 0.f));
        *reinterpret_cast<uint2v*>(hb + ((edge*128 + ot*32 + q*8) ^ swz)) = wv;  // ds_write_b64
      }
    }

    // ---- layer 1 + segment max, one center (32 edges) at a time ----
    #pragma unroll
    for (int cen = 0; cen < 2; ++cen){
      const int eA = (2*cen)*16 + lc;
      const int eB = (2*cen + 1)*16 + lc;
      const int sw = (lc & 7) << 4;
      bf16x8 a0A = *reinterpret_cast<const bf16x8*>(hb + ((eA*128      + q*16) ^ sw));
      bf16x8 a1A = *reinterpret_cast<const bf16x8*>(hb + ((eA*128 + 64 + q*16) ^ sw));
      bf16x8 a0B = *reinterpret_cast<const bf16x8*>(hb + ((eB*128      + q*16) ^ sw));
      bf16x8 a1B = *reinterpret_cast<const bf16x8*>(hb + ((eB*128 + 64 + q*16) ^ sw));

      f32x4 accA[4], accB[4];
      #pragma unroll
      for (int n2 = 0; n2 < 4; ++n2){
        f32x4 z = {0.f, 0.f, 0.f, 0.f};
        accA[n2] = z; accB[n2] = z;
      }
      #pragma unroll
      for (int n2 = 0; n2 < 4; ++n2){
        bf16x8 bw0 = *reinterpret_cast<const bf16x8*>(&b1w_lds[((0*4 + n2)*64 + lane)*8]);
        bf16x8 bw1 = *reinterpret_cast<const bf16x8*>(&b1w_lds[((1*4 + n2)*64 + lane)*8]);
        accA[n2] = __builtin_amdgcn_mfma_f32_16x16x32_bf16(a0A, bw0, accA[n2], 0,0,0);
        accA[n2] = __builtin_amdgcn_mfma_f32_16x16x32_bf16(a1A, bw1, accA[n2], 0,0,0);
        accB[n2] = __builtin_amdgcn_mfma_f32_16x16x32_bf16(a0B, bw0, accB[n2], 0,0,0);
        accB[n2] = __builtin_amdgcn_mfma_f32_16x16x32_bf16(a1B, bw1, accB[n2], 0,0,0);
      }

      float s0n, s1n, s2n, s3n;
      #pragma unroll
      for (int n2 = 0; n2 < 4; ++n2){
        float m0 = fmaxf(fmaxf(accA[n2][0], accB[n2][0]), fmaxf(accA[n2][1], accB[n2][1]));
        float m1 = fmaxf(fmaxf(accA[n2][2], accB[n2][2]), fmaxf(accA[n2][3], accB[n2][3]));
        float mm = fmaxf(m0, m1);
        mm = fmaxf(mm, __shfl_xor(mm, 16));
        mm = fmaxf(mm, __shfl_xor(mm, 32));
        if (n2 == 0) s0n = mm; else if (n2 == 1) s1n = mm; else if (n2 == 2) s2n = mm; else s3n = mm;
      }
      float v01 = (q & 1) ? s1n : s0n;
      float v23 = (q & 1) ? s3n : s2n;
      float v   = (q & 2) ? v23 : v01;   // select n2 == q -> out channel == lane
      v = fmaxf(v + bb1s, 0.f);          // bias folded after max
      pooled[(size_t)(cbase + cen)*64 + lane] = v;
    }

    b = bn;
  }
}

// ---------- kernel C: p=relu(pooled@Wq0+b); p=relu(p@Wq1+b); out=relu(det + p@Wo+bo) ----------
// 32 rows/block, 2 rows x 4(+4) cols per thread; Wo streamed from global (L1-hot).
__global__ __launch_bounds__(256) void kC(const float* __restrict__ det,
                                          const float* __restrict__ pooled,
                                          const float* __restrict__ Wq0, const float* __restrict__ bq0,
                                          const float* __restrict__ Wq1, const float* __restrict__ bq1,
                                          const float* __restrict__ Wo,  const float* __restrict__ bo,
                                          float* __restrict__ out){
  __shared__ float w0s[64*64];     // [k][c] 16 KB
  __shared__ float w1s[64*64];     // 16 KB
  __shared__ float pts[32*68];     // 8.7 KB
  __shared__ float p1s[32*68];     // 8.7 KB
  const int t  = threadIdx.x;
  const int r0 = blockIdx.x * 32;
  {
    const f32x4* s0 = reinterpret_cast<const f32x4*>(Wq0);
    const f32x4* s1 = reinterpret_cast<const f32x4*>(Wq1);
    #pragma unroll
    for (int i = 0; i < 4; ++i) reinterpret_cast<f32x4*>(w0s)[t + 256*i] = s0[t + 256*i];
    #pragma unroll
    for (int i = 0; i < 4; ++i) reinterpret_cast<f32x4*>(w1s)[t + 256*i] = s1[t + 256*i];
    #pragma unroll
    for (int i = 0; i < 2; ++i){
      int idx = t + 256*i;                 // 0..511
      int row = idx >> 4, c4l = (idx & 15) * 4;
      int gr = r0 + row; if (gr > N_DETS-1) gr = N_DETS-1;
      *reinterpret_cast<f32x4*>(&pts[row*68 + c4l]) =
        *reinterpret_cast<const f32x4*>(&pooled[(size_t)gr*64 + c4l]);
    }
  }
  __syncthreads();
  const int rg = t >> 4;            // rows rg*2, rg*2+1
  const int c4 = (t & 15) * 4;
  const int ra = rg*2, rb = rg*2 + 1;

  // q0
  f32x4 bq0v = *reinterpret_cast<const f32x4*>(&bq0[c4]);
  f32x4 qa = bq0v, qb = bq0v;
  for (int k = 0; k < 64; ++k){
    f32x4 wv = *reinterpret_cast<const f32x4*>(&w0s[k*64 + c4]);
    float pa = pts[ra*68 + k], pb = pts[rb*68 + k];
    qa[0]=fmaf(pa,wv[0],qa[0]); qa[1]=fmaf(pa,wv[1],qa[1]); qa[2]=fmaf(pa,wv[2],qa[2]); qa[3]=fmaf(pa,wv[3],qa[3]);
    qb[0]=fmaf(pb,wv[0],qb[0]); qb[1]=fmaf(pb,wv[1],qb[1]); qb[2]=fmaf(pb,wv[2],qb[2]); qb[3]=fmaf(pb,wv[3],qb[3]);
  }
  #pragma unroll
  for (int j = 0; j < 4; ++j){ qa[j]=fmaxf(qa[j],0.f); qb[j]=fmaxf(qb[j],0.f); }
  *reinterpret_cast<f32x4*>(&p1s[ra*68 + c4]) = qa;
  *reinterpret_cast<f32x4*>(&p1s[rb*68 + c4]) = qb;
  __syncthreads();

  // q1 (reads p1s, overwrites pts — pooled tile no longer needed)
  f32x4 bq1v = *reinterpret_cast<const f32x4*>(&bq1[c4]);
  f32x4 ua = bq1v, ub = bq1v;
  for (int k = 0; k < 64; ++k){
    f32x4 wv = *reinterpret_cast<const f32x4*>(&w1s[k*64 + c4]);
    float pa = p1s[ra*68 + k], pb = p1s[rb*68 + k];
    ua[0]=fmaf(pa,wv[0],ua[0]); ua[1]=fmaf(pa,wv[1],ua[1]); ua[2]=fmaf(pa,wv[2],ua[2]); ua[3]=fmaf(pa,wv[3],ua[3]);
    ub[0]=fmaf(pb,wv[0],ub[0]); ub[1]=fmaf(pb,wv[1],ub[1]); ub[2]=fmaf(pb,wv[2],ub[2]); ub[3]=fmaf(pb,wv[3],ub[3]);
  }
  #pragma unroll
  for (int j = 0; j < 4; ++j){ ua[j]=fmaxf(ua[j],0.f); ub[j]=fmaxf(ub[j],0.f); }
  *reinterpret_cast<f32x4*>(&pts[ra*68 + c4]) = ua;
  *reinterpret_cast<f32x4*>(&pts[rb*68 + c4]) = ub;
  __syncthreads();

  // Wo + residual; thread owns cols c4..+3 and 64+c4..+3 for rows ra, rb
  f32x4 boa = *reinterpret_cast<const f32x4*>(&bo[c4]);
  f32x4 bob = *reinterpret_cast<const f32x4*>(&bo[64 + c4]);
  f32x4 oa0 = boa, oa1 = bob, ob0 = boa, ob1 = bob;
  for (int k = 0; k < 64; ++k){
    f32x4 wa = *reinterpret_cast<const f32x4*>(&Wo[k*128 + c4]);
    f32x4 wb = *reinterpret_cast<const f32x4*>(&Wo[k*128 + 64 + c4]);
    float pa = pts[ra*68 + k], pb = pts[rb*68 + k];
    oa0[0]=fmaf(pa,wa[0],oa0[0]); oa0[1]=fmaf(pa,wa[1],oa0[1]); oa0[2]=fmaf(pa,wa[2],oa0[2]); oa0[3]=fmaf(pa,wa[3],oa0[3]);
    oa1[0]=fmaf(pa,wb[0],oa1[0]); oa1[1]=fmaf(pa,wb[1],oa1[1]); oa1[2]=fmaf(pa,wb[2],oa1[2]); oa1[3]=fmaf(pa,wb[3],oa1[3]);
    ob0[0]=fmaf(pb,wa[0],ob0[0]); ob0[1]=fmaf(pb,wa[1],ob0[1]); ob0[2]=fmaf(pb,wa[2],ob0[2]); ob0[3]=fmaf(pb,wa[3],ob0[3]);
    ob1[0]=fmaf(pb,wb[0],ob1[0]); ob1[1]=fmaf(pb,wb[1],ob1[1]); ob1[2]=fmaf(pb,wb[2],ob1[2]); ob1[3]=fmaf(pb,wb[3],ob1[3]);
  }
  #pragma unroll
  for (int rr = 0; rr < 2; ++rr){
    int gr = r0 + rg*2 + rr;
    if (gr < N_DETS){
      const float* dr = &det[(size_t)gr * 128];
      f32x4 d0 = *reinterpret_cast<const f32x4*>(&dr[c4]);
      f32x4 d1 = *reinterpret_cast<const f32x4*>(&dr[64 + c4]);
      f32x4 o0 = rr ? ob0 : oa0;
      f32x4 o1 = rr ? ob1 : oa1;
      f32x4 res0, res1;
      res0[0]=fmaxf(d0[0]+o0[0],0.f); res0[1]=fmaxf(d0[1]+o0[1],0.f);
      res0[2]=fmaxf(d0[2]+o0[2],0.f); res0[3]=fmaxf(d0[3]+o0[3],0.f);
      res1[0]=fmaxf(d1[0]+o1[0],0.f); res1[1]=fmaxf(d1[1]+o1[1],0.f);
      res1[2]=fmaxf(d1[2]+o1[2],0.f); res1[3]=fmaxf(d1[3]+o1[3],0.f);
      float* orow = &out[(size_t)gr * 128];
      *reinterpret_cast<f32x4*>(&orow[c4])      = res0;
      *reinterpret_cast<f32x4*>(&orow[64 + c4]) = res1;
    }
  }
}

// ---------- launch ----------
extern "C" void kernel_launch(void* const* d_in, const int* in_sizes, int n_in,
                              void* d_out, int out_size, void* d_ws, size_t ws_size,
                              hipStream_t stream){
  const float* det   = (const float*)d_in[0];
  // d_in[1] = cIdxs: repeat(arange(N_DETS), 32) — segments contiguous; not re-read
  const int*   nIdx  = (const int*)  d_in[2];
  const float* pfeat = (const float*)d_in[3];
  const float* W1    = (const float*)d_in[4];
  const float* b1    = (const float*)d_in[5];
  const float* Wp0   = (const float*)d_in[6];
  const float* bp0   = (const float*)d_in[7];
  const float* Wp1   = (const float*)d_in[8];
  const float* bp1   = (const float*)d_in[9];
  const float* Wq0   = (const float*)d_in[10];
  const float* bq0   = (const float*)d_in[11];
  const float* Wq1   = (const float*)d_in[12];
  const float* bq1   = (const float*)d_in[13];
  const float* Wo    = (const float*)d_in[14];
  const float* bo    = (const float*)d_in[15];
  float* out = (float*)d_out;

  // workspace: f1 bf16 3.2MB | packed weights 20KB | pooled fp32 12.8MB
  unsigned short* f1 = (unsigned short*)d_ws;
  unsigned short* wf = (unsigned short*)((char*)d_ws + 3200000);
  float* pooled      = (float*)((char*)d_ws + 3225600);

  kA<<<(N_DETS + 63)/64, 256, 0, stream>>>(det, W1, b1, Wp0, Wp1, f1, wf);
  kB<<<768,             256, 0, stream>>>(pfeat, nIdx, f1, wf, bp0, bp1, pooled);
  kC<<<(N_DETS + 31)/32, 256, 0, stream>>>(det, pooled, Wq0, bq0, Wq1, bq1, Wo, bo, out);
}